// Round 5
// baseline (321.643 us; speedup 1.0000x reference)
//
#include <hip/hip_runtime.h>
#include <cstdint>

// Problem constants (from the reference)
#define LL    200
#define QQ    21
#define MM    1024
#define START 133        // 2*L//3
#define NS    67         // L - START
#define RGH   0.01f
#define RGJ   0.01f

// ws layout:
//   [0,   256)  : 64 slots for sum(J^2)
//   [256, 512)  : 64 slots for sum(J*fij) (masked)
//   [512, 768)  : 64 slots for sum w*logZ
//   [1024, +LL*MM*4) : tokT (transposed tokens, [j][n])
#define SLOT_J2  0
#define SLOT_E   64
#define SLOT_LZ  128
#define TOKT_OFF 1024
#define WS_NEED (TOKT_OFF + (size_t)LL * MM * 4)

// LDS row stride 23 floats (odd!): gcd(23,32)=1 ->
//  - staging writes (lane-stride 23 floats) hit all 32 banks: conflict-free
//  - gather row starts 23b mod 32 distinct for all 21 b: conflict-free
//  - rows only 4B-aligned: gather via ds_read2_b32 pairs (compiler DS-combine),
//    11 LDS instructions per 21-float row, imm dword offsets.
#define RSTRIDE 23
#define TJ 16
#define LDSJ_FLOATS (TJ * QQ * RSTRIDE)   // 7728 floats = 30912 B -> 5 blocks/CU

__device__ __forceinline__ float block_reduce_sum_256(float v) {
  __shared__ float sm[4];
  #pragma unroll
  for (int off = 32; off > 0; off >>= 1) v += __shfl_down(v, off, 64);
  const int lane = threadIdx.x & 63;
  const int wv   = threadIdx.x >> 6;
  __syncthreads();
  if (lane == 0) sm[wv] = v;
  __syncthreads();
  float r = 0.0f;
  if (threadIdx.x == 0) r = sm[0] + sm[1] + sm[2] + sm[3];
  return r;  // valid in thread 0 only
}

__device__ __forceinline__ float block_reduce_sum_128(float v) {
  __shared__ float sm[2];
  #pragma unroll
  for (int off = 32; off > 0; off >>= 1) v += __shfl_down(v, off, 64);
  const int lane = threadIdx.x & 63;
  const int wv   = threadIdx.x >> 6;
  __syncthreads();
  if (lane == 0) sm[wv] = v;
  __syncthreads();
  float r = 0.0f;
  if (threadIdx.x == 0) r = sm[0] + sm[1];
  return r;  // valid in thread 0 only
}

// ---------------------------------------------------------------------------
// sum(J^2): pure branchless float4 stream over all 17.64M elements.
// ---------------------------------------------------------------------------
__global__ __launch_bounds__(256) void kern_jsq(
    const float* __restrict__ J, float* __restrict__ acc) {
  const float4* __restrict__ J4 = (const float4*)J;
  const int total4 = LL * QQ * LL * QQ / 4;   // 4,410,000
  float j2 = 0.0f;
  for (int f = blockIdx.x * 256 + threadIdx.x; f < total4; f += 2048 * 256) {
    const float4 v = J4[f];
    j2 += v.x * v.x + v.y * v.y + v.z * v.z + v.w * v.w;
  }
  const float t = block_reduce_sum_256(j2);
  if (threadIdx.x == 0) atomicAdd(acc + SLOT_J2 + (blockIdx.x & 63), t);
}

// ---------------------------------------------------------------------------
// sum(J*fij) over {i>=START, j<i}: grid (NS, QQ); block (i,a) streams the
// contiguous prefix (pos < i*21) of its 4200-float row. Branchless inner loop.
// ---------------------------------------------------------------------------
__global__ __launch_bounds__(256) void kern_jfij(
    const float* __restrict__ J, const float* __restrict__ fij,
    float* __restrict__ acc) {
  const int i = START + blockIdx.x;
  const int a = blockIdx.y;
  const size_t rb = (size_t)i * (QQ * LL * QQ) + (size_t)a * (LL * QQ);
  const float4* __restrict__ J4 = (const float4*)(J + rb);
  const float4* __restrict__ F4 = (const float4*)(fij + rb);
  const int lim  = i * QQ;
  const int lim4 = lim >> 2;
  const int rem  = lim & 3;
  float e = 0.0f;
  for (int f = threadIdx.x; f < lim4; f += 256) {
    const float4 v = J4[f];
    const float4 u = F4[f];
    e += v.x * u.x + v.y * u.y + v.z * u.z + v.w * u.w;
  }
  if ((int)threadIdx.x < rem) {
    const int p = lim4 * 4 + threadIdx.x;
    e += (J + rb)[p] * (fij + rb)[p];
  }
  const float t = block_reduce_sum_256(e);
  if (threadIdx.x == 0) atomicAdd(acc + SLOT_E + (blockIdx.x & 63), t);
}

// ---------------------------------------------------------------------------
// Token transpose: tokT[j][n] = X[n][j]
// ---------------------------------------------------------------------------
__global__ __launch_bounds__(256) void kern_tokT(
    const int* __restrict__ X, int* __restrict__ tokT) {
  const int idx = blockIdx.x * 256 + threadIdx.x;
  if (idx < LL * MM) {
    const int j = idx / MM;
    const int n = idx - j * MM;
    tokT[idx] = X[n * LL + j];
  }
}

// ---------------------------------------------------------------------------
// logz helpers: register-pipelined staging. Per tile: 21 a-rows x up to 336
// contiguous floats. Global bases are wave-uniform (SGPR); LDS write addrs
// are 3 precomputed VGPRs + imm a*4 -> ~zero address VALU.
// ---------------------------------------------------------------------------
__device__ __forceinline__ void stage_load(
    const float* __restrict__ Jib, int tj21, int t, float (&reg)[63]) {
  const bool v0 = (t < tj21), v1 = (t + 128 < tj21), v2 = (t + 256 < tj21);
  #pragma unroll
  for (int a = 0; a < QQ; ++a) {
    const float* src = Jib + a * (LL * QQ);
    if (v0) reg[a * 3 + 0] = src[t];
    if (v1) reg[a * 3 + 1] = src[t + 128];
    if (v2) reg[a * 3 + 2] = src[t + 256];
  }
}

__device__ __forceinline__ void stage_write(
    int tj21, int t, const float (&reg)[63], float* __restrict__ lds) {
  const bool v0 = (t < tj21), v1 = (t + 128 < tj21), v2 = (t + 256 < tj21);
  float* d0 = lds + (size_t)t * RSTRIDE;
  float* d1 = lds + (size_t)(t + 128) * RSTRIDE;
  float* d2 = lds + (size_t)(t + 256) * RSTRIDE;
  #pragma unroll
  for (int a = 0; a < QQ; ++a) {
    if (v0) d0[a] = reg[a * 3 + 0];
    if (v1) d1[a] = reg[a * 3 + 1];
    if (v2) d2[a] = reg[a * 3 + 2];
  }
}

__device__ __forceinline__ void tok_load(
    const int* __restrict__ tokT, const int* __restrict__ Xtok, int useT,
    int j0, int cnt, int n, int (&bo)[TJ]) {
  #pragma unroll
  for (int k = 0; k < TJ; ++k) {
    if (k < cnt) {
      const int j = j0 + k;
      const int b = useT ? tokT[j * MM + n] : Xtok[n * LL + j];
      bo[k] = k * (QQ * RSTRIDE) + b * RSTRIDE;   // row float-offset in LDS
    }
  }
}

__device__ __forceinline__ void gather16(
    const float* __restrict__ lds, const int (&bo)[TJ], int cnt,
    float (&lg)[QQ]) {
  #pragma unroll
  for (int jl = 0; jl < TJ; ++jl) {
    if (jl >= cnt) break;              // block-uniform
    const float* row = lds + bo[jl];
    #pragma unroll
    for (int a = 0; a < QQ; ++a) lg[a] += row[a];   // pairs -> ds_read2_b32
  }
}

// ---------------------------------------------------------------------------
// Fused logits+logsumexp. Grid (NS, 8) x 128: block = (site i, 128 seqs),
// all j inside the block. 30.9 KB LDS -> 5 resident blocks/CU (10 waves).
// Software pipeline: while gathering tile s from LDS, tile s+1's 63 floats
// + 16 tokens are in flight into registers.
// ---------------------------------------------------------------------------
__global__ __launch_bounds__(128, 3) void kern_logz(
    const float* __restrict__ J, const int* __restrict__ tokT,
    const int* __restrict__ Xtok, const int useT,
    const float* __restrict__ h, const float* __restrict__ w,
    float* __restrict__ acc) {
  __shared__ float ldsJ[LDSJ_FLOATS];
  const int i = START + blockIdx.x;
  const int t = threadIdx.x;
  const int n = blockIdx.y * 128 + t;
  const float* Ji = J + (size_t)i * (QQ * LL * QQ);

  const int nfull  = i / TJ;
  const int remtj  = i % TJ;
  const int ntiles = nfull + (remtj ? 1 : 0);

  float lg[QQ];
  #pragma unroll
  for (int a = 0; a < QQ; ++a) lg[a] = 0.0f;

  float reg[63];
  int bo[TJ], bn[TJ];

  stage_load(Ji, TJ * QQ, t, reg);                 // tile 0 (always full)
  tok_load(tokT, Xtok, useT, 0, TJ, n, bo);

  for (int s = 0; s < ntiles; ++s) {
    const int full  = (s < nfull);
    const int tj21  = full ? TJ * QQ : remtj * QQ;
    const int cnt   = full ? TJ : remtj;
    stage_write(tj21, t, reg, ldsJ);               // waits vmcnt internally
    __syncthreads();
    if (s + 1 < ntiles) {                          // prefetch next tile
      const int fulln = (s + 1 < nfull);
      const int j0n   = (s + 1) * TJ;
      stage_load(Ji + j0n * QQ, fulln ? TJ * QQ : remtj * QQ, t, reg);
      tok_load(tokT, Xtok, useT, j0n, fulln ? TJ : remtj, n, bn);
    }
    gather16(ldsJ, bo, cnt, lg);                   // overlaps in-flight loads
    #pragma unroll
    for (int k = 0; k < TJ; ++k) bo[k] = bn[k];
    __syncthreads();
  }

  // Epilogue: + h, logsumexp over the 21 states, weighted 2-wave block sum.
  const float* hi = h + i * QQ;
  float mx = -3.0e38f;
  #pragma unroll
  for (int a = 0; a < QQ; ++a) { lg[a] += hi[a]; mx = fmaxf(mx, lg[a]); }
  float s = 0.0f;
  #pragma unroll
  for (int a = 0; a < QQ; ++a) s += expf(lg[a] - mx);
  const float contrib = w[n] * (mx + logf(s));
  const float tot = block_reduce_sum_128(contrib);
  if (t == 0) atomicAdd(acc + SLOT_LZ + (blockIdx.x & 63), tot);
}

// ---------------------------------------------------------------------------
// Final combine: slot sums + h-side terms + weight normalization.
// ---------------------------------------------------------------------------
__global__ __launch_bounds__(256) void kern_final(
    const float* __restrict__ h, const float* __restrict__ fi,
    const float* __restrict__ w, const float* __restrict__ acc,
    float* __restrict__ out) {
  const int t = threadIdx.x;
  const float sj2 = block_reduce_sum_256(t < 64 ? acc[SLOT_J2 + t] : 0.0f);
  const float se  = block_reduce_sum_256(t < 64 ? acc[SLOT_E + t] : 0.0f);
  const float slz = block_reduce_sum_256(t < 64 ? acc[SLOT_LZ + t] : 0.0f);
  float hs = 0.0f, eh = 0.0f, ws = 0.0f;
  for (int idx = t; idx < LL * QQ; idx += 256) {
    const float hv = h[idx];
    hs += hv * hv;
    if (idx >= START * QQ) eh += fi[idx] * hv;
  }
  for (int idx = t; idx < MM; idx += 256) ws += w[idx];
  const float ths = block_reduce_sum_256(hs);
  const float teh = block_reduce_sum_256(eh);
  const float tws = block_reduce_sum_256(ws);
  if (t == 0) {
    const float energy = teh + se;
    const float nll = slz / tws - energy;
    out[0] = nll + RGH * ths + RGJ * sj2;
    out[1] = nll;
  }
}

extern "C" void kernel_launch(void* const* d_in, const int* in_sizes, int n_in,
                              void* d_out, int out_size, void* d_ws, size_t ws_size,
                              hipStream_t stream) {
  const int*   Xtok = (const int*)  d_in[0];
  const float* wts  = (const float*)d_in[1];
  const float* fi   = (const float*)d_in[2];
  const float* fij  = (const float*)d_in[3];
  const float* h    = (const float*)d_in[4];
  const float* J    = (const float*)d_in[5];
  float* out  = (float*)d_out;
  float* acc  = (float*)d_ws;
  int*   tokT = (int*)((char*)d_ws + TOKT_OFF);
  const int useT = (ws_size >= WS_NEED) ? 1 : 0;

  hipMemsetAsync(d_ws, 0, 1024, stream);  // zero the 3x64 accumulator slots
  if (useT) {
    kern_tokT<<<(LL * MM + 255) / 256, 256, 0, stream>>>(Xtok, tokT);
  }
  kern_jsq<<<2048, 256, 0, stream>>>(J, acc);
  kern_jfij<<<dim3(NS, QQ), 256, 0, stream>>>(J, fij, acc);
  kern_logz<<<dim3(NS, 8), 128, 0, stream>>>(J, tokT, Xtok, useT, h, wts, acc);
  kern_final<<<1, 256, 0, stream>>>(h, fi, wts, acc, out);
}

// Round 6
// 218.565 us; speedup vs baseline: 1.4716x; 1.4716x over previous
//
#include <hip/hip_runtime.h>
#include <cstdint>

// Problem constants (from the reference)
#define LL    200
#define QQ    21
#define MM    1024
#define START 133        // 2*L//3
#define NS    67         // L - START
#define RGH   0.01f
#define RGJ   0.01f

// ws layout:
//   [0, 1024)              : accumulator slots (3 x 64 fp32)
//   [1024, +LL*MM*4)       : tokT (transposed tokens, [j][n])
//   [TOKT end, +SLAB)      : partial-logits slab [y][iIdx][a][n] (plain stores)
#define SLOT_J2  0
#define SLOT_E   64
#define SLOT_LZ  128
#define TOKT_OFF 1024
#define TOKT_BYTES ((size_t)LL * MM * 4)
#define SLAB_OFF (TOKT_OFF + TOKT_BYTES)                  // 820224
#define SLAB_BYTES ((size_t)2 * NS * QQ * MM * 4)         // 11,526,144
#define WS_FULL (SLAB_OFF + SLAB_BYTES)                   // ~12.3 MB
#define WS_TOK  SLAB_OFF                                  // mono + tokT fallback

// LDS tile: raw a-major copy of J[i, a, j0:j0+12, :]. Plane = 12*21 = 252
// floats, padded to 256 dwords (1024 B) so:
//  - DMA: one full-wave global_load_lds(16B) covers a plane (lane*16B dest)
//  - gather: tile[a*256 + jl*21 + b] — lanes differ only in b -> <=21 distinct
//    consecutive dwords -> conflict-free; a-planes 4x64-dword apart -> read2st64
#define TJ 12
#define PLANE 256                      // dwords per a-plane
#define TILE_FLOATS (QQ * PLANE)       // 5376 floats = 21504 B

typedef const uint32_t __attribute__((address_space(1)))* gq_t;
typedef uint32_t __attribute__((address_space(3)))* lq_t;

__device__ __forceinline__ float block_reduce_sum_256(float v) {
  __shared__ float sm[4];
  #pragma unroll
  for (int off = 32; off > 0; off >>= 1) v += __shfl_down(v, off, 64);
  const int lane = threadIdx.x & 63;
  const int wv   = threadIdx.x >> 6;
  __syncthreads();
  if (lane == 0) sm[wv] = v;
  __syncthreads();
  float r = 0.0f;
  if (threadIdx.x == 0) r = sm[0] + sm[1] + sm[2] + sm[3];
  return r;  // valid in thread 0 only
}

// ---------------------------------------------------------------------------
// DMA one tile (21 a-planes) into LDS. Wave wv handles a = wv, wv+4, ...
// Lane guard: only lanes covering rem*21 floats are active (ceil/4); the
// <=3-float overread stays inside row a of slice i (proof: slack >= 21 floats
// since jend <= i <= 199 < 200).
// ---------------------------------------------------------------------------
__device__ __forceinline__ void dma_tile(
    const float* __restrict__ Ji, int j0, int rem, int wv, int lane,
    float* __restrict__ tile) {
  const int nlanes = (rem * QQ + 3) >> 2;
  if (lane < nlanes) {
    for (int a = wv; a < QQ; a += 4) {
      const float* g = Ji + a * (LL * QQ) + j0 * QQ + lane * 4;
      __builtin_amdgcn_global_load_lds((gq_t)g, (lq_t)(tile + a * PLANE),
                                       16, 0, 0);
    }
  }
}

__device__ __forceinline__ void tok_load(
    const int* __restrict__ tokT, const int* __restrict__ Xtok, int useT,
    int j0, int jend, int n, int (&bo)[TJ]) {
  #pragma unroll
  for (int k = 0; k < TJ; ++k) {
    if (j0 + k < jend) {
      const int j = j0 + k;
      const int b = useT ? tokT[j * MM + n] : Xtok[n * LL + j];
      bo[k] = k * QQ + b;              // dword offset within a plane
    }
  }
}

__device__ __forceinline__ void gather_tile(
    const float* __restrict__ tile, const int (&bo)[TJ], int rem,
    float (&lg)[QQ]) {
  #pragma unroll
  for (int jl = 0; jl < TJ; ++jl) {
    if (jl >= rem) break;              // block-uniform
    const float* p = tile + bo[jl];
    #pragma unroll
    for (int a = 0; a < QQ; ++a) lg[a] += p[a * PLANE];
  }
}

// ---------------------------------------------------------------------------
// Shared body. MONO=false: block = (i, jhalf y, 256-seq chunk z); partial
// logits -> plain stores to slab region owned by this (y,i,z). MONO=true:
// all j in block, logsumexp epilogue (ws-too-small fallback).
// Double-buffered DMA: issue tile s+1, gather tile s, one barrier per tile.
// ---------------------------------------------------------------------------
template <bool MONO>
__device__ __forceinline__ void logz_body(
    const float* __restrict__ J, const int* __restrict__ tokT,
    const int* __restrict__ Xtok, int useT, const float* __restrict__ h,
    const float* __restrict__ w, float* __restrict__ slab,
    float* __restrict__ acc, float (*lds)[TILE_FLOATS]) {
  const int iI = blockIdx.x;
  const int i  = START + iI;
  const int y  = MONO ? 0 : blockIdx.y;
  const int h0 = i >> 1;
  const int jbeg = MONO ? 0 : (y ? h0 : 0);
  const int jend = MONO ? i : (y ? i : h0);
  const int t = threadIdx.x, lane = t & 63, wv = t >> 6;
  const int n = blockIdx.z * 256 + t;
  const float* Ji = J + (size_t)i * (QQ * LL * QQ);
  const int ntiles = (jend - jbeg + TJ - 1) / TJ;

  float lg[QQ];
  #pragma unroll
  for (int a = 0; a < QQ; ++a) lg[a] = 0.0f;
  int boc[TJ], bon[TJ];

  dma_tile(Ji, jbeg, min(TJ, jend - jbeg), wv, lane, lds[0]);
  tok_load(tokT, Xtok, useT, jbeg, jend, n, boc);
  __syncthreads();                     // drains DMA(0)

  for (int s = 0; s < ntiles; ++s) {
    const int j0  = jbeg + s * TJ;
    const int rem = min(TJ, jend - j0);
    const bool more = (s + 1 < ntiles);
    if (more) {                        // prefetch next tile into other buffer
      const int j1 = j0 + TJ;
      dma_tile(Ji, j1, min(TJ, jend - j1), wv, lane, lds[(s + 1) & 1]);
      tok_load(tokT, Xtok, useT, j1, jend, n, bon);
    }
    gather_tile(lds[s & 1], boc, rem, lg);   // overlaps in-flight DMA
    if (more) {
      #pragma unroll
      for (int k = 0; k < TJ; ++k) boc[k] = bon[k];
    }
    __syncthreads();                   // DMA(s+1) done; buffer reuse safe
  }

  if (MONO) {
    const float* hi = h + i * QQ;
    float mx = -3.0e38f;
    #pragma unroll
    for (int a = 0; a < QQ; ++a) { lg[a] += hi[a]; mx = fmaxf(mx, lg[a]); }
    float sme = 0.0f;
    #pragma unroll
    for (int a = 0; a < QQ; ++a) sme += expf(lg[a] - mx);
    const float contrib = w[n] * (mx + logf(sme));
    const float tot = block_reduce_sum_256(contrib);
    if (t == 0) atomicAdd(acc + SLOT_LZ + (blockIdx.x & 63), tot);
  } else {
    float* dst = slab + (((size_t)y * NS + iI) * QQ) * MM + n;
    #pragma unroll
    for (int a = 0; a < QQ; ++a) dst[a * MM] = lg[a];   // coalesced, no atomics
  }
}

__global__ __launch_bounds__(256) void kern_logz_p1(
    const float* __restrict__ J, const int* __restrict__ tokT,
    float* __restrict__ slab) {
  __shared__ float lds[2][TILE_FLOATS];   // 43008 B -> 3 blocks/CU
  logz_body<false>(J, tokT, nullptr, 1, nullptr, nullptr, slab, nullptr, lds);
}

__global__ __launch_bounds__(256) void kern_logz_mono(
    const float* __restrict__ J, const int* __restrict__ tokT,
    const int* __restrict__ Xtok, int useT, const float* __restrict__ h,
    const float* __restrict__ w, float* __restrict__ acc) {
  __shared__ float lds[2][TILE_FLOATS];
  logz_body<true>(J, tokT, Xtok, useT, h, w, nullptr, acc, lds);
}

// ---------------------------------------------------------------------------
// Phase 2: combine the two j-half partials, logsumexp, weighted sum.
// ---------------------------------------------------------------------------
__global__ __launch_bounds__(128) void kern_logz_p2(
    const float* __restrict__ slab, const float* __restrict__ h,
    const float* __restrict__ w, float* __restrict__ acc) {
  const int iI = blockIdx.x;
  const int n  = blockIdx.y * 128 + threadIdx.x;
  const float* s0 = slab + ((size_t)iI * QQ) * MM + n;
  const float* s1 = slab + (((size_t)NS + iI) * QQ) * MM + n;
  const float* hi = h + (START + iI) * QQ;
  float lg[QQ];
  float mx = -3.0e38f;
  #pragma unroll
  for (int a = 0; a < QQ; ++a) {
    lg[a] = s0[a * MM] + s1[a * MM] + hi[a];
    mx = fmaxf(mx, lg[a]);
  }
  float sme = 0.0f;
  #pragma unroll
  for (int a = 0; a < QQ; ++a) sme += expf(lg[a] - mx);
  float v = w[n] * (mx + logf(sme));
  #pragma unroll
  for (int off = 32; off > 0; off >>= 1) v += __shfl_down(v, off, 64);
  __shared__ float sm[2];
  if ((threadIdx.x & 63) == 0) sm[threadIdx.x >> 6] = v;
  __syncthreads();
  if (threadIdx.x == 0)
    atomicAdd(acc + SLOT_LZ + (blockIdx.x & 63), sm[0] + sm[1]);
}

// ---------------------------------------------------------------------------
// Fused sum(J^2) (all of J) + sum(J*fij) ({i>=START, j<i} prefix rows).
// 1024 blocks x 256: ~17 independent float4/thread on the J^2 stream, then
// 1-2 full prefix rows per block. 2048 total atomics over 64+64 slots.
// ---------------------------------------------------------------------------
__global__ __launch_bounds__(256) void kern_jsum(
    const float* __restrict__ J, const float* __restrict__ fij,
    float* __restrict__ acc) {
  const int t = threadIdx.x;
  const float4* __restrict__ J4 = (const float4*)J;
  float j2 = 0.0f;
  for (int f = blockIdx.x * 256 + t; f < (LL * QQ * LL * QQ / 4);
       f += 1024 * 256) {
    const float4 v = J4[f];
    j2 += v.x * v.x + v.y * v.y + v.z * v.z + v.w * v.w;
  }
  float e = 0.0f;
  for (int r = blockIdx.x; r < NS * QQ; r += 1024) {
    const int iI = r / QQ;
    const int a  = r - iI * QQ;
    const int i  = START + iI;
    const size_t base = (size_t)i * (QQ * LL * QQ) + (size_t)a * (LL * QQ);
    const float4* __restrict__ Jb = (const float4*)(J + base);
    const float4* __restrict__ Fb = (const float4*)(fij + base);
    const int lim  = i * QQ;
    const int lim4 = lim >> 2;
    for (int f = t; f < lim4; f += 256) {
      const float4 v = Jb[f], u = Fb[f];
      e += v.x * u.x + v.y * u.y + v.z * u.z + v.w * u.w;
    }
    const int rem = lim & 3;
    if (t < rem) {
      const int p = lim4 * 4 + t;
      e += (J + base)[p] * (fij + base)[p];
    }
  }
  const float tj2 = block_reduce_sum_256(j2);
  const float te  = block_reduce_sum_256(e);
  if (t == 0) {
    atomicAdd(acc + SLOT_J2 + (blockIdx.x & 63), tj2);
    atomicAdd(acc + SLOT_E  + (blockIdx.x & 63), te);
  }
}

// ---------------------------------------------------------------------------
// Token transpose: tokT[j][n] = X[n][j]
// ---------------------------------------------------------------------------
__global__ __launch_bounds__(256) void kern_tokT(
    const int* __restrict__ X, int* __restrict__ tokT) {
  const int idx = blockIdx.x * 256 + threadIdx.x;
  if (idx < LL * MM) {
    const int j = idx / MM;
    const int n = idx - j * MM;
    tokT[idx] = X[n * LL + j];
  }
}

// ---------------------------------------------------------------------------
// Final combine: slot sums + h-side terms + weight normalization.
// ---------------------------------------------------------------------------
__global__ __launch_bounds__(256) void kern_final(
    const float* __restrict__ h, const float* __restrict__ fi,
    const float* __restrict__ w, const float* __restrict__ acc,
    float* __restrict__ out) {
  const int t = threadIdx.x;
  const float sj2 = block_reduce_sum_256(t < 64 ? acc[SLOT_J2 + t] : 0.0f);
  const float se  = block_reduce_sum_256(t < 64 ? acc[SLOT_E + t] : 0.0f);
  const float slz = block_reduce_sum_256(t < 64 ? acc[SLOT_LZ + t] : 0.0f);
  float hs = 0.0f, eh = 0.0f, ws = 0.0f;
  for (int idx = t; idx < LL * QQ; idx += 256) {
    const float hv = h[idx];
    hs += hv * hv;
    if (idx >= START * QQ) eh += fi[idx] * hv;
  }
  for (int idx = t; idx < MM; idx += 256) ws += w[idx];
  const float ths = block_reduce_sum_256(hs);
  const float teh = block_reduce_sum_256(eh);
  const float tws = block_reduce_sum_256(ws);
  if (t == 0) {
    const float energy = teh + se;
    const float nll = slz / tws - energy;
    out[0] = nll + RGH * ths + RGJ * sj2;
    out[1] = nll;
  }
}

extern "C" void kernel_launch(void* const* d_in, const int* in_sizes, int n_in,
                              void* d_out, int out_size, void* d_ws, size_t ws_size,
                              hipStream_t stream) {
  const int*   Xtok = (const int*)  d_in[0];
  const float* wts  = (const float*)d_in[1];
  const float* fi   = (const float*)d_in[2];
  const float* fij  = (const float*)d_in[3];
  const float* h    = (const float*)d_in[4];
  const float* J    = (const float*)d_in[5];
  float* out  = (float*)d_out;
  float* acc  = (float*)d_ws;
  int*   tokT = (int*)((char*)d_ws + TOKT_OFF);
  float* slab = (float*)((char*)d_ws + SLAB_OFF);

  hipMemsetAsync(d_ws, 0, 1024, stream);  // zero the 3x64 accumulator slots
  if (ws_size >= WS_FULL) {
    kern_tokT<<<(LL * MM + 255) / 256, 256, 0, stream>>>(Xtok, tokT);
    kern_jsum<<<1024, 256, 0, stream>>>(J, fij, acc);
    kern_logz_p1<<<dim3(NS, 2, 4), 256, 0, stream>>>(J, tokT, slab);
    kern_logz_p2<<<dim3(NS, 8), 128, 0, stream>>>(slab, h, wts, acc);
    kern_final<<<1, 256, 0, stream>>>(h, fi, wts, acc, out);
  } else if (ws_size >= WS_TOK) {
    kern_tokT<<<(LL * MM + 255) / 256, 256, 0, stream>>>(Xtok, tokT);
    kern_jsum<<<1024, 256, 0, stream>>>(J, fij, acc);
    kern_logz_mono<<<dim3(NS, 1, 4), 256, 0, stream>>>(J, tokT, Xtok, 1, h, wts, acc);
    kern_final<<<1, 256, 0, stream>>>(h, fi, wts, acc, out);
  } else {
    kern_jsum<<<1024, 256, 0, stream>>>(J, fij, acc);
    kern_logz_mono<<<dim3(NS, 1, 4), 256, 0, stream>>>(J, nullptr, Xtok, 0, h, wts, acc);
    kern_final<<<1, 256, 0, stream>>>(h, fi, wts, acc, out);
  }
}

// Round 7
// 206.999 us; speedup vs baseline: 1.5538x; 1.0559x over previous
//
#include <hip/hip_runtime.h>
#include <cstdint>

// Problem constants (from the reference)
#define LL    200
#define QQ    21
#define MM    1024
#define START 133        // 2*L//3
#define NS    67         // L - START
#define RGH   0.01f
#define RGJ   0.01f

// ws layout:
//   [0, 1024)              : accumulator slots (3 x 64 fp32)
//   [1024, +LL*MM*4)       : tokT (transposed tokens, [j][n])
//   [TOKT end, +SLAB)      : partial-logits slab [y][iIdx][a][n] (plain stores)
#define SLOT_J2  0
#define SLOT_E   64
#define SLOT_LZ  128
#define TOKT_OFF 1024
#define TOKT_BYTES ((size_t)LL * MM * 4)
#define SLAB_OFF (TOKT_OFF + TOKT_BYTES)
#define SLAB_BYTES ((size_t)2 * NS * QQ * MM * 4)
#define WS_FULL (SLAB_OFF + SLAB_BYTES)
#define WS_TOK  SLAB_OFF

// LDS tile: raw a-major copy of J[i, a, j0:j0+12, :]. Plane = 252 floats
// padded to 256 dwords (1024 B):
//  - DMA: full-wave global_load_lds(16B) fills a plane (lane*16B dest)
//  - gather: tile[a*256 + jl*21 + b] — lanes differ only in b -> <=21 distinct
//    consecutive dwords -> conflict-free (R6: SQ_LDS_BANK_CONFLICT == 0)
#define TJ 12
#define PLANE 256
#define TILE_FLOATS (QQ * PLANE)       // 21504 B/buffer

// mega grid: p1 blocks first (long), jsum filler blocks after
#define NB_P1 (NS * 8)                 // 536
#define NB_JS 1024

typedef const uint32_t __attribute__((address_space(1)))* gq_t;
typedef uint32_t __attribute__((address_space(3)))* lq_t;

__device__ __forceinline__ float block_reduce_sum_256(float v) {
  __shared__ float sm[4];
  #pragma unroll
  for (int off = 32; off > 0; off >>= 1) v += __shfl_down(v, off, 64);
  const int lane = threadIdx.x & 63;
  const int wv   = threadIdx.x >> 6;
  __syncthreads();
  if (lane == 0) sm[wv] = v;
  __syncthreads();
  float r = 0.0f;
  if (threadIdx.x == 0) r = sm[0] + sm[1] + sm[2] + sm[3];
  return r;  // valid in thread 0 only
}

// ---------------------------------------------------------------------------
// DMA one tile (21 a-planes) into LDS; <=3-float overread stays in-slice.
// ---------------------------------------------------------------------------
__device__ __forceinline__ void dma_tile(
    const float* __restrict__ Ji, int j0, int rem, int wv, int lane,
    float* __restrict__ tile) {
  const int nlanes = (rem * QQ + 3) >> 2;
  if (lane < nlanes) {
    for (int a = wv; a < QQ; a += 4) {
      const float* g = Ji + a * (LL * QQ) + j0 * QQ + lane * 4;
      __builtin_amdgcn_global_load_lds((gq_t)g, (lq_t)(tile + a * PLANE),
                                       16, 0, 0);
    }
  }
}

__device__ __forceinline__ void tok_load(
    const int* __restrict__ tokT, const int* __restrict__ Xtok, int useT,
    int j0, int jend, int n, int (&bo)[TJ]) {
  #pragma unroll
  for (int k = 0; k < TJ; ++k) {
    if (j0 + k < jend) {
      const int j = j0 + k;
      const int b = useT ? tokT[j * MM + n] : Xtok[n * LL + j];
      bo[k] = k * QQ + b;
    }
  }
}

__device__ __forceinline__ void gather_tile(
    const float* __restrict__ tile, const int (&bo)[TJ], int rem,
    float (&lg)[QQ]) {
  #pragma unroll
  for (int jl = 0; jl < TJ; ++jl) {
    if (jl >= rem) break;              // block-uniform
    const float* p = tile + bo[jl];
    #pragma unroll
    for (int a = 0; a < QQ; ++a) lg[a] += p[a * PLANE];
  }
}

// ---------------------------------------------------------------------------
// p1 body: block = (site iI, j-half y, 256-seq chunk z). Double-buffered DMA;
// partial logits -> plain coalesced stores to the (y,iI) slab region.
// MONO=true: all j + logsumexp epilogue (fallback path).
// ---------------------------------------------------------------------------
template <bool MONO>
__device__ __forceinline__ void logz_body(
    const float* __restrict__ J, const int* __restrict__ tokT,
    const int* __restrict__ Xtok, int useT, const float* __restrict__ h,
    const float* __restrict__ w, float* __restrict__ slab,
    float* __restrict__ acc, int iI, int y, int z,
    float (*lds)[TILE_FLOATS]) {
  const int i  = START + iI;
  const int h0 = i >> 1;
  const int jbeg = MONO ? 0 : (y ? h0 : 0);
  const int jend = MONO ? i : (y ? i : h0);
  const int t = threadIdx.x, lane = t & 63, wv = t >> 6;
  const int n = z * 256 + t;
  const float* Ji = J + (size_t)i * (QQ * LL * QQ);
  const int ntiles = (jend - jbeg + TJ - 1) / TJ;

  float lg[QQ];
  #pragma unroll
  for (int a = 0; a < QQ; ++a) lg[a] = 0.0f;
  int boc[TJ], bon[TJ];

  dma_tile(Ji, jbeg, min(TJ, jend - jbeg), wv, lane, lds[0]);
  tok_load(tokT, Xtok, useT, jbeg, jend, n, boc);
  __syncthreads();                     // drains DMA(0)

  for (int s = 0; s < ntiles; ++s) {
    const int j0  = jbeg + s * TJ;
    const int rem = min(TJ, jend - j0);
    const bool more = (s + 1 < ntiles);
    if (more) {
      const int j1 = j0 + TJ;
      dma_tile(Ji, j1, min(TJ, jend - j1), wv, lane, lds[(s + 1) & 1]);
      tok_load(tokT, Xtok, useT, j1, jend, n, bon);
    }
    gather_tile(lds[s & 1], boc, rem, lg);   // overlaps in-flight DMA
    if (more) {
      #pragma unroll
      for (int k = 0; k < TJ; ++k) boc[k] = bon[k];
    }
    __syncthreads();
  }

  if (MONO) {
    const float* hi = h + i * QQ;
    float mx = -3.0e38f;
    #pragma unroll
    for (int a = 0; a < QQ; ++a) { lg[a] += hi[a]; mx = fmaxf(mx, lg[a]); }
    float sme = 0.0f;
    #pragma unroll
    for (int a = 0; a < QQ; ++a) sme += expf(lg[a] - mx);
    const float contrib = w[n] * (mx + logf(sme));
    const float tot = block_reduce_sum_256(contrib);
    if (t == 0) atomicAdd(acc + SLOT_LZ + (iI & 63), tot);
  } else {
    float* dst = slab + (((size_t)y * NS + iI) * QQ) * MM + n;
    #pragma unroll
    for (int a = 0; a < QQ; ++a) dst[a * MM] = lg[a];
  }
}

// ---------------------------------------------------------------------------
// jsum body: sum(J^2) stream + sum(J*fij) prefix rows, grid-strided by jb.
// ---------------------------------------------------------------------------
__device__ __forceinline__ void jsum_body(
    const float* __restrict__ J, const float* __restrict__ fij,
    float* __restrict__ acc, int jb) {
  const int t = threadIdx.x;
  const float4* __restrict__ J4 = (const float4*)J;
  float j2 = 0.0f;
  for (int f = jb * 256 + t; f < (LL * QQ * LL * QQ / 4); f += NB_JS * 256) {
    const float4 v = J4[f];
    j2 += v.x * v.x + v.y * v.y + v.z * v.z + v.w * v.w;
  }
  float e = 0.0f;
  for (int r = jb; r < NS * QQ; r += NB_JS) {
    const int iI = r / QQ;
    const int a  = r - iI * QQ;
    const int i  = START + iI;
    const size_t base = (size_t)i * (QQ * LL * QQ) + (size_t)a * (LL * QQ);
    const float4* __restrict__ Jb = (const float4*)(J + base);
    const float4* __restrict__ Fb = (const float4*)(fij + base);
    const int lim  = i * QQ;
    const int lim4 = lim >> 2;
    for (int f = t; f < lim4; f += 256) {
      const float4 v = Jb[f], u = Fb[f];
      e += v.x * u.x + v.y * u.y + v.z * u.z + v.w * u.w;
    }
    const int rem = lim & 3;
    if (t < rem) {
      const int p = lim4 * 4 + t;
      e += (J + base)[p] * (fij + base)[p];
    }
  }
  const float tj2 = block_reduce_sum_256(j2);
  const float te  = block_reduce_sum_256(e);
  if (t == 0) {
    atomicAdd(acc + SLOT_J2 + (jb & 63), tj2);
    atomicAdd(acc + SLOT_E  + (jb & 63), te);
  }
}

// ---------------------------------------------------------------------------
// Fused kernel: blocks [0, NB_P1) run p1 (LDS-bound, long — dispatched
// first); blocks [NB_P1, NB_P1+NB_JS) run jsum (HBM-bound fillers). The two
// roles use disjoint pipes and overlap on the same CUs; jsum also fills
// p1's makespan tail.
// ---------------------------------------------------------------------------
__global__ __launch_bounds__(256) void kern_mega(
    const float* __restrict__ J, const float* __restrict__ fij,
    const int* __restrict__ tokT, float* __restrict__ slab,
    float* __restrict__ acc) {
  __shared__ float lds[2][TILE_FLOATS];
  const int bx = blockIdx.x;
  if (bx < NB_P1) {
    const int iI  = bx % NS;
    const int sub = bx / NS;           // 0..7
    logz_body<false>(J, tokT, nullptr, 1, nullptr, nullptr, slab, acc,
                     iI, sub & 1, sub >> 1, lds);
  } else {
    jsum_body(J, fij, acc, bx - NB_P1);
  }
}

// Fallback kernels (ws too small for slab)
__global__ __launch_bounds__(256) void kern_logz_mono(
    const float* __restrict__ J, const int* __restrict__ tokT,
    const int* __restrict__ Xtok, int useT, const float* __restrict__ h,
    const float* __restrict__ w, float* __restrict__ acc) {
  __shared__ float lds[2][TILE_FLOATS];
  logz_body<true>(J, tokT, Xtok, useT, h, w, nullptr, acc,
                  blockIdx.x, 0, blockIdx.z, lds);
}

__global__ __launch_bounds__(256) void kern_jsum(
    const float* __restrict__ J, const float* __restrict__ fij,
    float* __restrict__ acc) {
  jsum_body(J, fij, acc, blockIdx.x);
}

// ---------------------------------------------------------------------------
// Phase 2: combine j-half partials, logsumexp, weighted sum.
// ---------------------------------------------------------------------------
__global__ __launch_bounds__(128) void kern_logz_p2(
    const float* __restrict__ slab, const float* __restrict__ h,
    const float* __restrict__ w, float* __restrict__ acc) {
  const int iI = blockIdx.x;
  const int n  = blockIdx.y * 128 + threadIdx.x;
  const float* s0 = slab + ((size_t)iI * QQ) * MM + n;
  const float* s1 = slab + (((size_t)NS + iI) * QQ) * MM + n;
  const float* hi = h + (START + iI) * QQ;
  float lg[QQ];
  float mx = -3.0e38f;
  #pragma unroll
  for (int a = 0; a < QQ; ++a) {
    lg[a] = s0[a * MM] + s1[a * MM] + hi[a];
    mx = fmaxf(mx, lg[a]);
  }
  float sme = 0.0f;
  #pragma unroll
  for (int a = 0; a < QQ; ++a) sme += expf(lg[a] - mx);
  float v = w[n] * (mx + logf(sme));
  #pragma unroll
  for (int off = 32; off > 0; off >>= 1) v += __shfl_down(v, off, 64);
  __shared__ float sm[2];
  if ((threadIdx.x & 63) == 0) sm[threadIdx.x >> 6] = v;
  __syncthreads();
  if (threadIdx.x == 0)
    atomicAdd(acc + SLOT_LZ + (blockIdx.x & 63), sm[0] + sm[1]);
}

// ---------------------------------------------------------------------------
// Token transpose: tokT[j][n] = X[n][j]
// ---------------------------------------------------------------------------
__global__ __launch_bounds__(256) void kern_tokT(
    const int* __restrict__ X, int* __restrict__ tokT) {
  const int idx = blockIdx.x * 256 + threadIdx.x;
  if (idx < LL * MM) {
    const int j = idx / MM;
    const int n = idx - j * MM;
    tokT[idx] = X[n * LL + j];
  }
}

// ---------------------------------------------------------------------------
// Final combine: slot sums + h-side terms + weight normalization.
// ---------------------------------------------------------------------------
__global__ __launch_bounds__(256) void kern_final(
    const float* __restrict__ h, const float* __restrict__ fi,
    const float* __restrict__ w, const float* __restrict__ acc,
    float* __restrict__ out) {
  const int t = threadIdx.x;
  const float sj2 = block_reduce_sum_256(t < 64 ? acc[SLOT_J2 + t] : 0.0f);
  const float se  = block_reduce_sum_256(t < 64 ? acc[SLOT_E + t] : 0.0f);
  const float slz = block_reduce_sum_256(t < 64 ? acc[SLOT_LZ + t] : 0.0f);
  float hs = 0.0f, eh = 0.0f, ws = 0.0f;
  for (int idx = t; idx < LL * QQ; idx += 256) {
    const float hv = h[idx];
    hs += hv * hv;
    if (idx >= START * QQ) eh += fi[idx] * hv;
  }
  for (int idx = t; idx < MM; idx += 256) ws += w[idx];
  const float ths = block_reduce_sum_256(hs);
  const float teh = block_reduce_sum_256(eh);
  const float tws = block_reduce_sum_256(ws);
  if (t == 0) {
    const float energy = teh + se;
    const float nll = slz / tws - energy;
    out[0] = nll + RGH * ths + RGJ * sj2;
    out[1] = nll;
  }
}

extern "C" void kernel_launch(void* const* d_in, const int* in_sizes, int n_in,
                              void* d_out, int out_size, void* d_ws, size_t ws_size,
                              hipStream_t stream) {
  const int*   Xtok = (const int*)  d_in[0];
  const float* wts  = (const float*)d_in[1];
  const float* fi   = (const float*)d_in[2];
  const float* fij  = (const float*)d_in[3];
  const float* h    = (const float*)d_in[4];
  const float* J    = (const float*)d_in[5];
  float* out  = (float*)d_out;
  float* acc  = (float*)d_ws;
  int*   tokT = (int*)((char*)d_ws + TOKT_OFF);
  float* slab = (float*)((char*)d_ws + SLAB_OFF);

  hipMemsetAsync(d_ws, 0, 1024, stream);  // zero the 3x64 accumulator slots
  if (ws_size >= WS_FULL) {
    kern_tokT<<<(LL * MM + 255) / 256, 256, 0, stream>>>(Xtok, tokT);
    kern_mega<<<NB_P1 + NB_JS, 256, 0, stream>>>(J, fij, tokT, slab, acc);
    kern_logz_p2<<<dim3(NS, 8), 128, 0, stream>>>(slab, h, wts, acc);
    kern_final<<<1, 256, 0, stream>>>(h, fi, wts, acc, out);
  } else if (ws_size >= WS_TOK) {
    kern_tokT<<<(LL * MM + 255) / 256, 256, 0, stream>>>(Xtok, tokT);
    kern_jsum<<<NB_JS, 256, 0, stream>>>(J, fij, acc);
    kern_logz_mono<<<dim3(NS, 1, 4), 256, 0, stream>>>(J, tokT, Xtok, 1, h, wts, acc);
    kern_final<<<1, 256, 0, stream>>>(h, fi, wts, acc, out);
  } else {
    kern_jsum<<<NB_JS, 256, 0, stream>>>(J, fij, acc);
    kern_logz_mono<<<dim3(NS, 1, 4), 256, 0, stream>>>(J, nullptr, Xtok, 0, h, wts, acc);
    kern_final<<<1, 256, 0, stream>>>(h, fi, wts, acc, out);
  }
}